// Round 4
// baseline (69.046 us; speedup 1.0000x reference)
//
#include <hip/hip_runtime.h>
#include <math.h>

#define Bn 64
#define Ln 350
#define Kn 8
#define Dn 300
#define Cn 20
#define SPLIT 32
#define PAD_IDX 1
#define NEG_BIG (-1e18f)

typedef float v4f __attribute__((ext_vector_type(4)));

// ---------------------------------------------------------------------------
// Kernel A: per (b,l): M[d] = max_k( mask(ew[k]*nbr[k,d]) ), combined =
// (1-ir)*M + ir*node_emb, accumulate sum over this block's l-slice.
// PARTIAL=true : write block partial to part[(b*SPLIT+sidx)*Dn + d]
// PARTIAL=false: atomicAdd into s[b*Dn + d] (requires zeroed ws)
// Block = 256 threads = 4 waves.
// ---------------------------------------------------------------------------
template <bool PARTIAL>
__global__ __launch_bounds__(256, 6) void mp_reduce(
    const int* __restrict__ node_sets,
    const float* __restrict__ emb_node,
    const float* __restrict__ edge_w,
    const float* __restrict__ emb_nbr,
    const float* __restrict__ info_rate,
    float* __restrict__ ws)
{
    __shared__ __align__(16) float sAcc[4][Dn + 4];

    const int bid  = blockIdx.x;
    const int b    = bid / SPLIT;
    const int sidx = bid % SPLIT;
    const int tid  = threadIdx.x;
    const int wave = tid >> 6;   // 0..3
    const int lane = tid & 63;
    const bool has1 = (lane < (Dn / 4 - 64));   // 75 quads; 11 in tail
    const int q0 = 4 * lane;
    const int q1 = 256 + 4 * lane;

    v4f acc0 = (v4f)(0.f);
    v4f acc1 = (v4f)(0.f);

    for (int j = wave;; j += 4) {
        const int l = sidx + j * SPLIT;
        if (l >= Ln) break;
        const size_t row = (size_t)b * Ln + l;

        // wave-uniform scalars (uniform addr -> broadcast; 2x float4)
        const float* ewp = edge_w + row * Kn;
        const v4f ew0 = *reinterpret_cast<const v4f*>(ewp);
        const v4f ew1 = *reinterpret_cast<const v4f*>(ewp + 4);
        const float ewv[Kn] = {ew0.x, ew0.y, ew0.z, ew0.w, ew1.x, ew1.y, ew1.z, ew1.w};

        const int node = node_sets[row];
        const float ir = (node == PAD_IDX) ? 1.0f : info_rate[node];
        const float om = 1.0f - ir;

        const float* nb = emb_nbr + row * (size_t)(Kn * Dn);
        const float* en = emb_node + row * (size_t)Dn;

        // ---- quad 0: d = 4*lane (covers d < 256)
        {
            v4f m = (v4f)(NEG_BIG);
            #pragma unroll
            for (int k = 0; k < Kn; ++k) {
                const v4f v = *reinterpret_cast<const v4f*>(nb + k * Dn + q0);
                const float w = ewv[k];
                float x0 = w * v.x, x1 = w * v.y, x2 = w * v.z, x3 = w * v.w;
                x0 = (x0 == 0.f) ? NEG_BIG : x0;
                x1 = (x1 == 0.f) ? NEG_BIG : x1;
                x2 = (x2 == 0.f) ? NEG_BIG : x2;
                x3 = (x3 == 0.f) ? NEG_BIG : x3;
                m.x = fmaxf(m.x, x0);
                m.y = fmaxf(m.y, x1);
                m.z = fmaxf(m.z, x2);
                m.w = fmaxf(m.w, x3);
            }
            const v4f e = *reinterpret_cast<const v4f*>(en + q0);
            acc0.x += om * m.x + ir * e.x;
            acc0.y += om * m.y + ir * e.y;
            acc0.z += om * m.z + ir * e.z;
            acc0.w += om * m.w + ir * e.w;
        }

        // ---- quad 1: d = 256 + 4*lane (lanes 0..10 only)
        if (has1) {
            v4f m = (v4f)(NEG_BIG);
            #pragma unroll
            for (int k = 0; k < Kn; ++k) {
                const v4f v = *reinterpret_cast<const v4f*>(nb + k * Dn + q1);
                const float w = ewv[k];
                float x0 = w * v.x, x1 = w * v.y, x2 = w * v.z, x3 = w * v.w;
                x0 = (x0 == 0.f) ? NEG_BIG : x0;
                x1 = (x1 == 0.f) ? NEG_BIG : x1;
                x2 = (x2 == 0.f) ? NEG_BIG : x2;
                x3 = (x3 == 0.f) ? NEG_BIG : x3;
                m.x = fmaxf(m.x, x0);
                m.y = fmaxf(m.y, x1);
                m.z = fmaxf(m.z, x2);
                m.w = fmaxf(m.w, x3);
            }
            const v4f e = *reinterpret_cast<const v4f*>(en + q1);
            acc1.x += om * m.x + ir * e.x;
            acc1.y += om * m.y + ir * e.y;
            acc1.z += om * m.z + ir * e.z;
            acc1.w += om * m.w + ir * e.w;
        }
    }

    // per-wave partials -> LDS (disjoint rows)
    *reinterpret_cast<v4f*>(&sAcc[wave][q0]) = acc0;
    if (has1) *reinterpret_cast<v4f*>(&sAcc[wave][q1]) = acc1;
    __syncthreads();

    if (PARTIAL) {
        float* dst = ws + (size_t)bid * Dn;
        for (int d = tid; d < Dn; d += 256)
            dst[d] = sAcc[0][d] + sAcc[1][d] + sAcc[2][d] + sAcc[3][d];
    } else {
        for (int d = tid; d < Dn; d += 256) {
            const float sum = sAcc[0][d] + sAcc[1][d] + sAcc[2][d] + sAcc[3][d];
            atomicAdd(&ws[b * Dn + d], sum);
        }
    }
}

// ---------------------------------------------------------------------------
// Kernel B: reduce NPART partials -> s[b,:], then
// x[b,c] = relu(dot(s, W[c]) + bias[c]); softmax over C=20. One block per b.
// Block = 256 threads = 4 WAVES (wave = 64 lanes on CDNA).
// ---------------------------------------------------------------------------
template <int NPART>
__global__ __launch_bounds__(256) void mp_head(
    const float* __restrict__ part,
    const float* __restrict__ Wm,
    const float* __restrict__ bias,
    float* __restrict__ out)
{
    __shared__ __align__(16) float wsum[4][Dn + 4];
    __shared__ __align__(16) float ssh[Dn + 4];
    __shared__ float xsh[Cn];

    const int b = blockIdx.x;
    const int t = threadIdx.x;
    const int wave = t >> 6;   // 0..3
    const int lane = t & 63;
    const bool has1 = (lane < (Dn / 4 - 64));
    const int q0 = 4 * lane;
    const int q1 = 256 + 4 * lane;

    if (NPART >= 4) {
        // phase 1: each of the 4 waves sums NPART/4 partials (float4, coalesced)
        constexpr int PPW = (NPART >= 4) ? NPART / 4 : 1;
        v4f a0 = (v4f)(0.f), a1 = (v4f)(0.f);
        #pragma unroll
        for (int p = 0; p < PPW; ++p) {
            const float* src = part + ((size_t)b * NPART + wave * PPW + p) * Dn;
            a0 += *reinterpret_cast<const v4f*>(src + q0);
            if (has1) a1 += *reinterpret_cast<const v4f*>(src + q1);
        }
        *reinterpret_cast<v4f*>(&wsum[wave][q0]) = a0;
        if (has1) *reinterpret_cast<v4f*>(&wsum[wave][q1]) = a1;
        __syncthreads();

        // phase 2: total across the 4 wave rows
        for (int d = t; d < Dn; d += 256)
            ssh[d] = wsum[0][d] + wsum[1][d] + wsum[2][d] + wsum[3][d];
    } else {
        for (int d = t; d < Dn; d += 256) ssh[d] = part[(size_t)b * Dn + d];
    }
    __syncthreads();

    // phase 3: classes round-robin over 4 waves (5 iters each), float4 dot
    for (int c = wave; c < Cn; c += 4) {
        const float* wr = Wm + (size_t)c * Dn;
        float acc = 0.f;
        {
            const v4f wv = *reinterpret_cast<const v4f*>(wr + q0);
            const v4f sv = *reinterpret_cast<const v4f*>(&ssh[q0]);
            acc += wv.x * sv.x + wv.y * sv.y + wv.z * sv.z + wv.w * sv.w;
        }
        if (has1) {
            const v4f wv = *reinterpret_cast<const v4f*>(wr + q1);
            const v4f sv = *reinterpret_cast<const v4f*>(&ssh[q1]);
            acc += wv.x * sv.x + wv.y * sv.y + wv.z * sv.z + wv.w * sv.w;
        }
        #pragma unroll
        for (int off = 32; off >= 1; off >>= 1)
            acc += __shfl_xor(acc, off, 64);
        if (lane == 0) xsh[c] = fmaxf(acc + bias[c], 0.f);
    }
    __syncthreads();

    // phase 4: softmax over C=20
    if (t < Cn) {
        float mx = xsh[0];
        #pragma unroll
        for (int i = 1; i < Cn; ++i) mx = fmaxf(mx, xsh[i]);
        float sum = 0.f;
        #pragma unroll
        for (int i = 0; i < Cn; ++i) sum += expf(xsh[i] - mx);
        out[b * Cn + t] = expf(xsh[t] - mx) / sum;
    }
}

extern "C" void kernel_launch(void* const* d_in, const int* in_sizes, int n_in,
                              void* d_out, int out_size, void* d_ws, size_t ws_size,
                              hipStream_t stream) {
    const int*   node_sets = (const int*)d_in[0];
    const float* emb_node  = (const float*)d_in[1];
    const float* edge_w    = (const float*)d_in[2];
    const float* emb_nbr   = (const float*)d_in[3];
    const float* info_rate = (const float*)d_in[4];
    const float* Wm        = (const float*)d_in[5];
    const float* bias      = (const float*)d_in[6];
    float* out  = (float*)d_out;
    float* ws   = (float*)d_ws;

    const size_t need = (size_t)Bn * SPLIT * Dn * sizeof(float);
    if (ws_size >= need) {
        // partials path: no memset, no atomics
        mp_reduce<true><<<dim3(Bn * SPLIT), 256, 0, stream>>>(
            node_sets, emb_node, edge_w, emb_nbr, info_rate, ws);
        mp_head<SPLIT><<<dim3(Bn), 256, 0, stream>>>(ws, Wm, bias, out);
    } else {
        // fallback: zeroed accumulator + atomics
        hipMemsetAsync(d_ws, 0, (size_t)Bn * Dn * sizeof(float), stream);
        mp_reduce<false><<<dim3(Bn * SPLIT), 256, 0, stream>>>(
            node_sets, emb_node, edge_w, emb_nbr, info_rate, ws);
        mp_head<1><<<dim3(Bn), 256, 0, stream>>>(ws, Wm, bias, out);
    }
}

// Round 5
// 49.214 us; speedup vs baseline: 1.4030x; 1.4030x over previous
//
#include <hip/hip_runtime.h>
#include <math.h>

#define Bn 64
#define Ln 350
#define Kn 8
#define Dn 300
#define Cn 20
#define SPLIT 16
#define PAD_IDX 1
#define NEG_BIG (-1e18f)

typedef float v4f __attribute__((ext_vector_type(4)));

// ---------------------------------------------------------------------------
// Kernel A: per (b,l): M[d] = max_k( mask(ew[k]*nbr[k,d]) ), combined =
// (1-ir)*M + ir*node_emb, accumulate sum over this block's l-slice.
// PARTIAL=true : write block partial to part[(b*SPLIT+sidx)*Dn + d]
// PARTIAL=false: atomicAdd into s[b*Dn + d] (requires zeroed ws)
// Block = 256 threads = 4 waves. NO min-waves bound: let the allocator keep
// all 8 k-loads in flight (round-4's (256,6) capped VGPRs and cost 15 us).
// ---------------------------------------------------------------------------
template <bool PARTIAL>
__global__ __launch_bounds__(256) void mp_reduce(
    const int* __restrict__ node_sets,
    const float* __restrict__ emb_node,
    const float* __restrict__ edge_w,
    const float* __restrict__ emb_nbr,
    const float* __restrict__ info_rate,
    float* __restrict__ ws)
{
    __shared__ __align__(16) float sAcc[4][Dn + 4];

    const int bid  = blockIdx.x;
    const int b    = bid / SPLIT;
    const int sidx = bid % SPLIT;
    const int tid  = threadIdx.x;
    const int wave = tid >> 6;   // 0..3
    const int lane = tid & 63;
    const bool has1 = (lane < (Dn / 4 - 64));   // 75 quads; 11 in tail
    const int q0 = 4 * lane;
    const int q1 = 256 + 4 * lane;

    v4f acc0 = (v4f)(0.f);
    v4f acc1 = (v4f)(0.f);

    for (int j = wave;; j += 4) {
        const int l = sidx + j * SPLIT;
        if (l >= Ln) break;
        const size_t row = (size_t)b * Ln + l;

        // wave-uniform scalars (uniform addr -> broadcast; 2x float4)
        const float* ewp = edge_w + row * Kn;
        const v4f ew0 = *reinterpret_cast<const v4f*>(ewp);
        const v4f ew1 = *reinterpret_cast<const v4f*>(ewp + 4);
        const float ewv[Kn] = {ew0.x, ew0.y, ew0.z, ew0.w, ew1.x, ew1.y, ew1.z, ew1.w};

        const int node = node_sets[row];
        const float ir = (node == PAD_IDX) ? 1.0f : info_rate[node];
        const float om = 1.0f - ir;

        const float* nb = emb_nbr + row * (size_t)(Kn * Dn);
        const float* en = emb_node + row * (size_t)Dn;

        // ---- quad 0: d = 4*lane (covers d < 256)
        {
            v4f m = (v4f)(NEG_BIG);
            #pragma unroll
            for (int k = 0; k < Kn; ++k) {
                const v4f v = *reinterpret_cast<const v4f*>(nb + k * Dn + q0);
                const float w = ewv[k];
                float x0 = w * v.x, x1 = w * v.y, x2 = w * v.z, x3 = w * v.w;
                x0 = (x0 == 0.f) ? NEG_BIG : x0;
                x1 = (x1 == 0.f) ? NEG_BIG : x1;
                x2 = (x2 == 0.f) ? NEG_BIG : x2;
                x3 = (x3 == 0.f) ? NEG_BIG : x3;
                m.x = fmaxf(m.x, x0);
                m.y = fmaxf(m.y, x1);
                m.z = fmaxf(m.z, x2);
                m.w = fmaxf(m.w, x3);
            }
            const v4f e = *reinterpret_cast<const v4f*>(en + q0);
            acc0.x += om * m.x + ir * e.x;
            acc0.y += om * m.y + ir * e.y;
            acc0.z += om * m.z + ir * e.z;
            acc0.w += om * m.w + ir * e.w;
        }

        // ---- quad 1: d = 256 + 4*lane (lanes 0..10 only)
        if (has1) {
            v4f m = (v4f)(NEG_BIG);
            #pragma unroll
            for (int k = 0; k < Kn; ++k) {
                const v4f v = *reinterpret_cast<const v4f*>(nb + k * Dn + q1);
                const float w = ewv[k];
                float x0 = w * v.x, x1 = w * v.y, x2 = w * v.z, x3 = w * v.w;
                x0 = (x0 == 0.f) ? NEG_BIG : x0;
                x1 = (x1 == 0.f) ? NEG_BIG : x1;
                x2 = (x2 == 0.f) ? NEG_BIG : x2;
                x3 = (x3 == 0.f) ? NEG_BIG : x3;
                m.x = fmaxf(m.x, x0);
                m.y = fmaxf(m.y, x1);
                m.z = fmaxf(m.z, x2);
                m.w = fmaxf(m.w, x3);
            }
            const v4f e = *reinterpret_cast<const v4f*>(en + q1);
            acc1.x += om * m.x + ir * e.x;
            acc1.y += om * m.y + ir * e.y;
            acc1.z += om * m.z + ir * e.z;
            acc1.w += om * m.w + ir * e.w;
        }
    }

    // per-wave partials -> LDS (disjoint rows)
    *reinterpret_cast<v4f*>(&sAcc[wave][q0]) = acc0;
    if (has1) *reinterpret_cast<v4f*>(&sAcc[wave][q1]) = acc1;
    __syncthreads();

    if (PARTIAL) {
        float* dst = ws + (size_t)bid * Dn;
        for (int d = tid; d < Dn; d += 256)
            dst[d] = sAcc[0][d] + sAcc[1][d] + sAcc[2][d] + sAcc[3][d];
    } else {
        for (int d = tid; d < Dn; d += 256) {
            const float sum = sAcc[0][d] + sAcc[1][d] + sAcc[2][d] + sAcc[3][d];
            atomicAdd(&ws[b * Dn + d], sum);
        }
    }
}

// ---------------------------------------------------------------------------
// Kernel B: reduce NPART partials -> s[b,:], then
// x[b,c] = relu(dot(s, W[c]) + bias[c]); softmax over C=20. One block per b.
// Block = 256 threads = 4 WAVES (wave = 64 lanes on CDNA).
// ---------------------------------------------------------------------------
template <int NPART>
__global__ __launch_bounds__(256) void mp_head(
    const float* __restrict__ part,
    const float* __restrict__ Wm,
    const float* __restrict__ bias,
    float* __restrict__ out)
{
    __shared__ __align__(16) float wsum[4][Dn + 4];
    __shared__ __align__(16) float ssh[Dn + 4];
    __shared__ float xsh[Cn];

    const int b = blockIdx.x;
    const int t = threadIdx.x;
    const int wave = t >> 6;   // 0..3
    const int lane = t & 63;
    const bool has1 = (lane < (Dn / 4 - 64));
    const int q0 = 4 * lane;
    const int q1 = 256 + 4 * lane;

    if (NPART >= 4) {
        // phase 1: each of the 4 waves sums NPART/4 partials (float4, coalesced)
        constexpr int PPW = (NPART >= 4) ? NPART / 4 : 1;
        v4f a0 = (v4f)(0.f), a1 = (v4f)(0.f);
        #pragma unroll
        for (int p = 0; p < PPW; ++p) {
            const float* src = part + ((size_t)b * NPART + wave * PPW + p) * Dn;
            a0 += *reinterpret_cast<const v4f*>(src + q0);
            if (has1) a1 += *reinterpret_cast<const v4f*>(src + q1);
        }
        *reinterpret_cast<v4f*>(&wsum[wave][q0]) = a0;
        if (has1) *reinterpret_cast<v4f*>(&wsum[wave][q1]) = a1;
        __syncthreads();

        // phase 2: total across the 4 wave rows
        for (int d = t; d < Dn; d += 256)
            ssh[d] = wsum[0][d] + wsum[1][d] + wsum[2][d] + wsum[3][d];
    } else {
        for (int d = t; d < Dn; d += 256) ssh[d] = part[(size_t)b * Dn + d];
    }
    __syncthreads();

    // phase 3: classes round-robin over 4 waves (5 iters each), float4 dot
    for (int c = wave; c < Cn; c += 4) {
        const float* wr = Wm + (size_t)c * Dn;
        float acc = 0.f;
        {
            const v4f wv = *reinterpret_cast<const v4f*>(wr + q0);
            const v4f sv = *reinterpret_cast<const v4f*>(&ssh[q0]);
            acc += wv.x * sv.x + wv.y * sv.y + wv.z * sv.z + wv.w * sv.w;
        }
        if (has1) {
            const v4f wv = *reinterpret_cast<const v4f*>(wr + q1);
            const v4f sv = *reinterpret_cast<const v4f*>(&ssh[q1]);
            acc += wv.x * sv.x + wv.y * sv.y + wv.z * sv.z + wv.w * sv.w;
        }
        #pragma unroll
        for (int off = 32; off >= 1; off >>= 1)
            acc += __shfl_xor(acc, off, 64);
        if (lane == 0) xsh[c] = fmaxf(acc + bias[c], 0.f);
    }
    __syncthreads();

    // phase 4: softmax over C=20
    if (t < Cn) {
        float mx = xsh[0];
        #pragma unroll
        for (int i = 1; i < Cn; ++i) mx = fmaxf(mx, xsh[i]);
        float sum = 0.f;
        #pragma unroll
        for (int i = 0; i < Cn; ++i) sum += expf(xsh[i] - mx);
        out[b * Cn + t] = expf(xsh[t] - mx) / sum;
    }
}

extern "C" void kernel_launch(void* const* d_in, const int* in_sizes, int n_in,
                              void* d_out, int out_size, void* d_ws, size_t ws_size,
                              hipStream_t stream) {
    const int*   node_sets = (const int*)d_in[0];
    const float* emb_node  = (const float*)d_in[1];
    const float* edge_w    = (const float*)d_in[2];
    const float* emb_nbr   = (const float*)d_in[3];
    const float* info_rate = (const float*)d_in[4];
    const float* Wm        = (const float*)d_in[5];
    const float* bias      = (const float*)d_in[6];
    float* out  = (float*)d_out;
    float* ws   = (float*)d_ws;

    const size_t need = (size_t)Bn * SPLIT * Dn * sizeof(float);
    if (ws_size >= need) {
        // partials path: no memset, no atomics
        mp_reduce<true><<<dim3(Bn * SPLIT), 256, 0, stream>>>(
            node_sets, emb_node, edge_w, emb_nbr, info_rate, ws);
        mp_head<SPLIT><<<dim3(Bn), 256, 0, stream>>>(ws, Wm, bias, out);
    } else {
        // fallback: zeroed accumulator + atomics
        hipMemsetAsync(d_ws, 0, (size_t)Bn * Dn * sizeof(float), stream);
        mp_reduce<false><<<dim3(Bn * SPLIT), 256, 0, stream>>>(
            node_sets, emb_node, edge_w, emb_nbr, info_rate, ws);
        mp_head<1><<<dim3(Bn), 256, 0, stream>>>(ws, Wm, bias, out);
    }
}